// Round 13
// baseline (1268.784 us; speedup 1.0000x reference)
//
#include <hip/hip_runtime.h>
#include <math.h>

namespace {

constexpr int N_  = 32768;   // nodes
constexpr int S_  = 1024;    // nodes per graph
constexpr int B_  = 32;      // graphs
constexpr int E_  = 262144;  // edges
constexpr int C_  = 128;     // hidden
constexpr int ND_ = 64;
constexpr int PE_ = 16;
constexpr int ED_ = 16;
constexpr float LNE = 1e-5f;

typedef __attribute__((ext_vector_type(8))) short short8;
typedef __attribute__((ext_vector_type(4))) float floatx4;

__device__ inline float gelu_tanh(float v) {
  const float c = 0.7978845608028654f;
  return 0.5f * v * (1.0f + tanhf(c * (v + 0.044715f * v * v * v)));
}

__device__ inline unsigned short f2bf_u(float f) {
  unsigned u = __float_as_uint(f);
  u += 0x7fff + ((u >> 16) & 1);
  return (unsigned short)(u >> 16);
}

__device__ inline float bf2f(unsigned short v) {
  return __uint_as_float(((unsigned)v) << 16);
}

__device__ inline float block_sum128(float v, float* red, int t) {
  red[t] = v;
  __syncthreads();
#pragma unroll
  for (int off = 64; off > 0; off >>= 1) {
    if (t < off) red[t] += red[t + off];
    __syncthreads();
  }
  float r = red[0];
  __syncthreads();
  return r;
}

// ---------------- zero (graph-capture-safe memset) ----------------
__global__ void k_zero(float4* __restrict__ p, int n4) {
  int i = blockIdx.x * 256 + threadIdx.x;
  if (i < n4) p[i] = make_float4(0.f, 0.f, 0.f, 0.f);
}

// ---------------- counting sort by dst ----------------
__global__ void k_count(const int* __restrict__ dst, int* __restrict__ hist) {
  int e = blockIdx.x * 256 + threadIdx.x;
  if (e < E_) atomicAdd(&hist[dst[e]], 1);
}

__global__ __launch_bounds__(1024) void k_scan(int* __restrict__ hist, int* __restrict__ binStart) {
  __shared__ int sums[1024];
  int t = threadIdx.x;
  int base = t * 32;
  int loc[32];
  int s = 0;
#pragma unroll
  for (int i = 0; i < 32; ++i) { loc[i] = s; s += hist[base + i]; }
  sums[t] = s;
  __syncthreads();
  for (int off = 1; off < 1024; off <<= 1) {
    int v = (t >= off) ? sums[t - off] : 0;
    __syncthreads();
    sums[t] += v;
    __syncthreads();
  }
  int excl = sums[t] - s;
#pragma unroll
  for (int i = 0; i < 32; ++i) {
    int v = excl + loc[i];
    binStart[base + i] = v;
    hist[base + i] = v;  // cursor (in-place)
  }
  if (t == 1023) binStart[32768] = sums[1023];
}

__global__ void k_scatter(const int* __restrict__ dst, int* __restrict__ cursor,
                          int* __restrict__ perm) {
  int e = blockIdx.x * 256 + threadIdx.x;
  if (e < E_) {
    int p = atomicAdd(&cursor[dst[e]], 1);
    perm[p] = e;
  }
}

// gather edge data into sorted order, bf16 (coalesced writes; one-time)
__global__ void k_gather_edges(const float* __restrict__ ea, const int* __restrict__ src,
                               const int* __restrict__ dst, const int* __restrict__ perm,
                               unsigned short* __restrict__ ea_b, int* __restrict__ src_s,
                               int* __restrict__ dst_s) {
  int p = blockIdx.x * 256 + threadIdx.x;  // edge slot
  if (p >= E_) return;
  int e = perm[p];
  const float4* s = (const float4*)(ea + (size_t)e * ED_);
  unsigned short* d = ea_b + (size_t)p * ED_;
#pragma unroll
  for (int i = 0; i < 4; ++i) {
    float4 v = s[i];
    ushort4 u;
    u.x = f2bf_u(v.x); u.y = f2bf_u(v.y); u.z = f2bf_u(v.z); u.w = f2bf_u(v.w);
    *(ushort4*)(d + i * 4) = u;
  }
  src_s[p] = src[e];
  dst_s[p] = dst[e];
}

// ---------------- fold edge_w2 into elin; emit TRANSPOSED bf16 weight ----------------
__global__ void k_fuse_w(const float* __restrict__ w2, const float* __restrict__ b2,
                         const float* __restrict__ elin_w, const float* __restrict__ elin_b,
                         unsigned short* __restrict__ fw2t, float* __restrict__ fb2) {
  int t = threadIdx.x;
  int bid = blockIdx.x;
  int layer = bid / (C_ + 1);
  int k = bid % (C_ + 1);
  const float* el = elin_w + (size_t)layer * C_ * C_;
  if (k < C_) {
    float a = 0.0f;
    for (int m = 0; m < C_; ++m) a += w2[k * C_ + m] * el[m * C_ + t];
    fw2t[(size_t)layer * C_ * C_ + t * C_ + k] = f2bf_u(a);
  } else {
    float a = elin_b[layer * C_ + t];
    for (int m = 0; m < C_; ++m) a += b2[m] * el[m * C_ + t];
    fb2[layer * C_ + t] = a;
  }
}

// ---------------- prep edge_w1 transposed bf16 with zero-padded K (16->32) ----------------
__global__ void k_prep_ew1(const float* __restrict__ ew1, unsigned short* __restrict__ ew1t) {
  int n = blockIdx.x;        // 128
  int k = threadIdx.x;       // 32
  ew1t[n * 32 + k] = (k < ED_) ? f2bf_u(ew1[k * C_ + n]) : (unsigned short)0;
}

// ---------------- prep: bf16-transpose all node-path weights ----------------
__global__ void k_prep(const float* __restrict__ gin_w1, const float* __restrict__ gin_w2,
                       const float* __restrict__ aqkv_w, const float* __restrict__ aout_w,
                       const float* __restrict__ mlp_w1, const float* __restrict__ mlp_w2,
                       unsigned short* __restrict__ wt) {
  int t = threadIdx.x;
  int bid = blockIdx.x;
  int l = bid / 1152;
  int r = bid % 1152;
  unsigned short* base = wt + (size_t)l * 163840;
  if (r < 128) {
    base[r * 128 + t] = f2bf_u(gin_w1[(size_t)l * 16384 + t * 128 + r]);
  } else if (r < 256) {
    int n = r - 128;
    base[16384 + n * 128 + t] = f2bf_u(gin_w2[(size_t)l * 16384 + t * 128 + n]);
  } else if (r < 640) {
    int n = r - 256;
    base[32768 + n * 128 + t] = f2bf_u(aqkv_w[(size_t)l * 49152 + t * 384 + n]);
  } else if (r < 768) {
    int n = r - 640;
    base[81920 + n * 128 + t] = f2bf_u(aout_w[(size_t)l * 16384 + t * 128 + n]);
  } else if (r < 1024) {
    int n = r - 768;
    base[98304 + n * 128 + t] = f2bf_u(mlp_w1[(size_t)l * 32768 + t * 256 + n]);
  } else {
    int n = r - 1024;
    base[131072 + n * 256 + t]       = f2bf_u(mlp_w2[(size_t)l * 32768 + t * 128 + n]);
    base[131072 + n * 256 + 128 + t] = f2bf_u(mlp_w2[(size_t)l * 32768 + (t + 128) * 128 + n]);
  }
}

// ---------------- node encoder (scalar fp32) ----------------
__global__ void k_node_enc(const float* __restrict__ xin, const float* __restrict__ pe,
                           const float* __restrict__ w1, const float* __restrict__ b1,
                           const float* __restrict__ w2, const float* __restrict__ b2,
                           float* __restrict__ xout) {
  __shared__ float inL[4][80];
  __shared__ float hidL[4][C_];
  int t = threadIdx.x;
  int row0 = blockIdx.x * 4;
#pragma unroll
  for (int r = 0; r < 4; ++r) {
    int row = row0 + r;
    if (t < ND_) inL[r][t] = xin[(size_t)row * ND_ + t];
    else if (t < 80) inL[r][t] = pe[(size_t)row * PE_ + (t - ND_)];
  }
  __syncthreads();
  float acc[4];
  float bb = b1[t];
#pragma unroll
  for (int r = 0; r < 4; ++r) acc[r] = bb;
  for (int k = 0; k < 80; ++k) {
    float wv = w1[k * C_ + t];
#pragma unroll
    for (int r = 0; r < 4; ++r) acc[r] += inL[r][k] * wv;
  }
#pragma unroll
  for (int r = 0; r < 4; ++r) hidL[r][t] = fmaxf(acc[r], 0.0f);
  __syncthreads();
  float bb2 = b2[t];
#pragma unroll
  for (int r = 0; r < 4; ++r) acc[r] = bb2;
  for (int k = 0; k < C_; ++k) {
    float wv = w2[k * C_ + t];
#pragma unroll
    for (int r = 0; r < 4; ++r) acc[r] += hidL[r][k] * wv;
  }
#pragma unroll
  for (int r = 0; r < 4; ++r) xout[(size_t)(row0 + r) * C_ + t] = acc[r];
}

// ------------- MFMA edge pipeline v4 (r12-verified) -------------
__global__ __launch_bounds__(256) void k_edge_mfma(
    const unsigned short* __restrict__ ea_b, const float* __restrict__ x,
    const int* __restrict__ src_s, const int* __restrict__ dst_s,
    const unsigned short* __restrict__ ew1t, const float* __restrict__ eb1,
    const unsigned short* __restrict__ fw2t, const float* __restrict__ fb2,
    float* __restrict__ agg) {
  __shared__ unsigned short eaL[64][32];
  __shared__ unsigned short buf[64][136];
  __shared__ unsigned short xrL[64][136];
  __shared__ int srcL[64], dstL[64];
  int tid = threadIdx.x;
  int e0 = blockIdx.x * 64;

  if (tid < 64) { srcL[tid] = src_s[e0 + tid]; dstL[tid] = dst_s[e0 + tid]; }
  if (tid < 128) {
    int r = tid >> 1, hf = tid & 1;
    *(short8*)&eaL[r][hf * 8] = *(const short8*)(ea_b + (size_t)(e0 + r) * ED_ + hf * 8);
  } else {
    int r = (tid - 128) >> 1, hf = (tid - 128) & 1;
    short8 z = {0, 0, 0, 0, 0, 0, 0, 0};
    *(short8*)&eaL[r][16 + hf * 8] = z;
  }
  __syncthreads();

  float4 xv[8];
#pragma unroll
  for (int it = 0; it < 8; ++it) {
    int idx = it * 256 + tid;
    int r = idx >> 5, c4 = idx & 31;
    xv[it] = *(const float4*)(x + (size_t)srcL[r] * C_ + c4 * 4);
  }

  int lane = tid & 63;
  int w = tid >> 6;
  int li = lane & 15;
  int quad = lane >> 4;
  int r0 = w * 16;

  short8 aE = *(const short8*)&eaL[r0 + li][quad * 8];
#pragma unroll
  for (int t8 = 0; t8 < 8; ++t8) {
    short8 bE = *(const short8*)(ew1t + (size_t)(t8 * 16 + li) * 32 + quad * 8);
    floatx4 z = {0.f, 0.f, 0.f, 0.f};
    floatx4 h = __builtin_amdgcn_mfma_f32_16x16x32_bf16(aE, bE, z, 0, 0, 0);
    float bv = eb1[t8 * 16 + li];
#pragma unroll
    for (int reg = 0; reg < 4; ++reg)
      buf[r0 + quad * 4 + reg][t8 * 16 + li] = f2bf_u(fmaxf(h[reg] + bv, 0.f));
  }

#pragma unroll
  for (int it = 0; it < 8; ++it) {
    int idx = it * 256 + tid;
    int r = idx >> 5, c4 = idx & 31;
    ushort4 u;
    u.x = f2bf_u(xv[it].x); u.y = f2bf_u(xv[it].y);
    u.z = f2bf_u(xv[it].z); u.w = f2bf_u(xv[it].w);
    *(ushort4*)&xrL[r][c4 * 4] = u;
  }
  __syncthreads();

  short8 aK[4];
#pragma unroll
  for (int k4 = 0; k4 < 4; ++k4)
    aK[k4] = *(const short8*)&buf[r0 + li][k4 * 32 + quad * 8];

  float fbv[8];
#pragma unroll
  for (int t8 = 0; t8 < 8; ++t8) fbv[t8] = fb2[t8 * 16 + li];

#pragma unroll
  for (int t8 = 0; t8 < 8; ++t8) {
    floatx4 acc = {0.f, 0.f, 0.f, 0.f};
    const unsigned short* bp = fw2t + (size_t)(t8 * 16 + li) * C_ + quad * 8;
#pragma unroll
    for (int k4 = 0; k4 < 4; ++k4) {
      short8 bf = *(const short8*)(bp + k4 * 32);
      acc = __builtin_amdgcn_mfma_f32_16x16x32_bf16(aK[k4], bf, acc, 0, 0, 0);
    }
    int n = t8 * 16 + li;
#pragma unroll
    for (int reg = 0; reg < 4; ++reg) {
      int cr = r0 + quad * 4 + reg;
      float v = fmaxf(acc[reg] + fbv[t8] + bf2f(xrL[cr][n]), 0.0f);
      buf[cr][n] = f2bf_u(v);
    }
  }
  __syncthreads();

  {
    int col = tid & 127;
    int rbase = (tid >> 7) * 32;
    float run = bf2f(buf[rbase][col]);
    int cur = dstL[rbase];
    for (int r = 1; r < 32; ++r) {
      int rr = rbase + r;
      int d = dstL[rr];
      float v = bf2f(buf[rr][col]);
      if (d != cur) {
        atomicAdd(&agg[(size_t)cur * C_ + col], run);
        run = v; cur = d;
      } else {
        run += v;
      }
    }
    atomicAdd(&agg[(size_t)cur * C_ + col], run);
  }
}

// ------------- FUSED GIN + QKV (LN1 residual from LDS) -------------
__global__ __launch_bounds__(256) void k_ginqkv(
    const float* __restrict__ x, const float* __restrict__ agg,
    const unsigned short* __restrict__ w1t, const float* __restrict__ b1,
    const unsigned short* __restrict__ w2t, const float* __restrict__ b2,
    const float* __restrict__ g, const float* __restrict__ bln,
    const float* __restrict__ epsarr, int layer, float* __restrict__ hl,
    const unsigned short* __restrict__ qkvt, const float* __restrict__ qb,
    unsigned short* __restrict__ qkvb) {
  __shared__ unsigned short inL[64][136];
  __shared__ unsigned short xbL[64][136];
  int tid = threadIdx.x;
  int row0 = blockIdx.x * 64;
  float epsv = 1.0f + epsarr[layer];
#pragma unroll
  for (int i = 0; i < 8; ++i) {
    int p = i * 256 + tid;
    int r = p >> 5, c4 = p & 31;
    float4 xa = *(const float4*)(x + (size_t)(row0 + r) * C_ + c4 * 4);
    float4 ag = *(const float4*)(agg + (size_t)(row0 + r) * C_ + c4 * 4);
    ushort4 ux;
    ux.x = f2bf_u(xa.x); ux.y = f2bf_u(xa.y); ux.z = f2bf_u(xa.z); ux.w = f2bf_u(xa.w);
    *(ushort4*)&xbL[r][c4 * 4] = ux;
    ushort4 u;
    u.x = f2bf_u(epsv * xa.x + ag.x);
    u.y = f2bf_u(epsv * xa.y + ag.y);
    u.z = f2bf_u(epsv * xa.z + ag.z);
    u.w = f2bf_u(epsv * xa.w + ag.w);
    *(ushort4*)&inL[r][c4 * 4] = u;
  }
  __syncthreads();
  int lane = tid & 63, w = tid >> 6, li = lane & 15, quad = lane >> 4;
  int r0 = w * 16;

  short8 aK[4];
#pragma unroll
  for (int k4 = 0; k4 < 4; ++k4) aK[k4] = *(const short8*)&inL[r0 + li][k4 * 32 + quad * 8];
#pragma unroll
  for (int t8 = 0; t8 < 8; ++t8) {
    floatx4 acc = {0.f, 0.f, 0.f, 0.f};
    const unsigned short* bp = w1t + (size_t)(t8 * 16 + li) * 128 + quad * 8;
#pragma unroll
    for (int k4 = 0; k4 < 4; ++k4) {
      short8 bf = *(const short8*)(bp + k4 * 32);
      acc = __builtin_amdgcn_mfma_f32_16x16x32_bf16(aK[k4], bf, acc, 0, 0, 0);
    }
    float bv = b1[t8 * 16 + li];
#pragma unroll
    for (int reg = 0; reg < 4; ++reg)
      inL[r0 + quad * 4 + reg][t8 * 16 + li] = f2bf_u(fmaxf(acc[reg] + bv, 0.f));
  }
  short8 aK2[4];
#pragma unroll
  for (int k4 = 0; k4 < 4; ++k4) aK2[k4] = *(const short8*)&inL[r0 + li][k4 * 32 + quad * 8];
  floatx4 acc2[8];
#pragma unroll
  for (int t8 = 0; t8 < 8; ++t8) acc2[t8] = (floatx4){0.f, 0.f, 0.f, 0.f};
#pragma unroll
  for (int t8 = 0; t8 < 8; ++t8) {
    const unsigned short* bp = w2t + (size_t)(t8 * 16 + li) * 128 + quad * 8;
#pragma unroll
    for (int k4 = 0; k4 < 4; ++k4) {
      short8 bf = *(const short8*)(bp + k4 * 32);
      acc2[t8] = __builtin_amdgcn_mfma_f32_16x16x32_bf16(aK2[k4], bf, acc2[t8], 0, 0, 0);
    }
  }
  float gv[8], blv[8], b2v[8];
#pragma unroll
  for (int t8 = 0; t8 < 8; ++t8) {
    int col = t8 * 16 + li;
    gv[t8] = g[col]; blv[t8] = bln[col]; b2v[t8] = b2[col];
  }
#pragma unroll
  for (int reg = 0; reg < 4; ++reg) {
    int row = row0 + r0 + quad * 4 + reg;
    int lr = r0 + quad * 4 + reg;
    float v[8], s = 0.f, s2 = 0.f;
#pragma unroll
    for (int t8 = 0; t8 < 8; ++t8) {
      float xv = bf2f(xbL[lr][t8 * 16 + li]);  // LDS residual (was global x re-read)
      v[t8] = acc2[t8][reg] + b2v[t8] + xv;
      s += v[t8]; s2 += v[t8] * v[t8];
    }
#pragma unroll
    for (int m = 1; m <= 8; m <<= 1) { s += __shfl_xor(s, m); s2 += __shfl_xor(s2, m); }
    float mu = s * (1.0f / C_);
    float var = s2 * (1.0f / C_) - mu * mu;
    float inv = rsqrtf(var + LNE);
#pragma unroll
    for (int t8 = 0; t8 < 8; ++t8)
      hl[(size_t)row * C_ + t8 * 16 + li] = (v[t8] - mu) * inv * gv[t8] + blv[t8];
  }

  short8 aQ[4];
#pragma unroll
  for (int k4 = 0; k4 < 4; ++k4) aQ[k4] = *(const short8*)&xbL[r0 + li][k4 * 32 + quad * 8];
#pragma unroll
  for (int t8 = 0; t8 < 24; ++t8) {
    floatx4 acc = {0.f, 0.f, 0.f, 0.f};
    const unsigned short* bp = qkvt + (size_t)(t8 * 16 + li) * 128 + quad * 8;
#pragma unroll
    for (int k4 = 0; k4 < 4; ++k4) {
      short8 bf = *(const short8*)(bp + k4 * 32);
      acc = __builtin_amdgcn_mfma_f32_16x16x32_bf16(aQ[k4], bf, acc, 0, 0, 0);
    }
    int col = t8 * 16 + li;
    float bv = qb[col];
#pragma unroll
    for (int reg = 0; reg < 4; ++reg) {
      int row = row0 + r0 + quad * 4 + reg;
      qkvb[(size_t)row * 384 + col] = f2bf_u(acc[reg] + bv);
    }
  }
}

// ------------- MFMA flash attention v3 -> bf16 output -------------
__global__ __launch_bounds__(256) void k_attn_mfma(const unsigned short* __restrict__ qkvb,
                                                   unsigned short* __restrict__ attno_b) {
  __shared__ unsigned short kL[2][32][40];
  __shared__ unsigned short vT[2][32][40];
  __shared__ unsigned short pL[4][16][40];
  int tid = threadIdx.x;
  int lane = tid & 63;
  int w = tid >> 6;
  int li = lane & 15;
  int quad = lane >> 4;
  int bid = blockIdx.x;
  int b = (bid & 7) * 4 + ((bid >> 3) & 3);
  int rest = bid >> 5;
  int h = rest & 3;
  int qt = rest >> 2;
  int qbase = b * S_ + qt * 64 + w * 16;

  short8 qA = *(const short8*)(qkvb + (size_t)(qbase + li) * 384 + h * 32 + quad * 8);

  floatx4 o0 = {0.f, 0.f, 0.f, 0.f}, o1 = {0.f, 0.f, 0.f, 0.f};
  float lsum[4] = {0.f, 0.f, 0.f, 0.f};
  const float scale = 0.17677669529663687f;

  int half = tid >> 7;
  int tt = tid & 127;
  int j = tt >> 2;
  int seg = tt & 3;
  int vcol = (((j >> 3) ^ seg) & 3) * 8 + (j & 7);
  int vg0 = ((quad ^ (li >> 3)) & 3) * 8;
  int vg1 = ((quad ^ (2 + (li >> 3))) & 3) * 8;

  const unsigned short* pbase = qkvb + (half ? 256 : 128) + h * 32 + seg * 8;

  short8 val = *(const short8*)(pbase + (size_t)(b * S_ + 0 * 32 + j) * 384);

  for (int kc = 0; kc < 32; ++kc) {
    int buf = kc & 1;
    if (half == 0) {
      *(short8*)&kL[buf][j][seg * 8] = val;
    } else {
#pragma unroll
      for (int i = 0; i < 8; ++i) vT[buf][seg * 8 + i][vcol] = (unsigned short)val[i];
    }
    __syncthreads();
    if (kc < 31)
      val = *(const short8*)(pbase + (size_t)(b * S_ + (kc + 1) * 32 + j) * 384);
    short8 kB0 = *(const short8*)&kL[buf][li][quad * 8];
    short8 kB1 = *(const short8*)&kL[buf][16 + li][quad * 8];
    floatx4 z = {0.f, 0.f, 0.f, 0.f};
    floatx4 s0 = __builtin_amdgcn_mfma_f32_16x16x32_bf16(qA, kB0, z, 0, 0, 0);
    floatx4 s1 = __builtin_amdgcn_mfma_f32_16x16x32_bf16(qA, kB1, z, 0, 0, 0);
#pragma unroll
    for (int r = 0; r < 4; ++r) {
      float p0 = __expf(s0[r] * scale);
      float p1 = __expf(s1[r] * scale);
      lsum[r] += p0 + p1;
      pL[w][quad * 4 + r][li] = f2bf_u(p0);
      pL[w][quad * 4 + r][16 + li] = f2bf_u(p1);
    }
    short8 pA  = *(const short8*)&pL[w][li][quad * 8];
    short8 vB0 = *(const short8*)&vT[buf][li][vg0];
    short8 vB1 = *(const short8*)&vT[buf][16 + li][vg1];
    o0 = __builtin_amdgcn_mfma_f32_16x16x32_bf16(pA, vB0, o0, 0, 0, 0);
    o1 = __builtin_amdgcn_mfma_f32_16x16x32_bf16(pA, vB1, o1, 0, 0, 0);
  }
#pragma unroll
  for (int r = 0; r < 4; ++r) {
    float l = lsum[r];
#pragma unroll
    for (int msk = 1; msk <= 8; msk <<= 1) l += __shfl_xor(l, msk);
    float inv = 1.0f / l;
    size_t row = (size_t)(qbase + quad * 4 + r);
    attno_b[row * C_ + h * 32 + li] = f2bf_u(o0[r] * inv);
    attno_b[row * C_ + h * 32 + 16 + li] = f2bf_u(o1[r] * inv);
  }
}

// ------------- FUSED attn-out-proj + LN2 + FFN + LN3 (bf16 attno in, x cached in regs) ----
__global__ __launch_bounds__(256) void k_aoffn(
    const unsigned short* __restrict__ attno_b, float* __restrict__ x,
    const float* __restrict__ hl,
    const unsigned short* __restrict__ aot, const float* __restrict__ ab,
    const float* __restrict__ g2, const float* __restrict__ bl2,
    const unsigned short* __restrict__ w1t, const float* __restrict__ b1,
    const unsigned short* __restrict__ w2t, const float* __restrict__ b2,
    const float* __restrict__ g3, const float* __restrict__ bl3) {
  __shared__ unsigned short inL[64][136];
  __shared__ unsigned short hidL[64][264];
  int tid = threadIdx.x;
  int row0 = blockIdx.x * 64;
#pragma unroll
  for (int i = 0; i < 4; ++i) {
    int p = i * 256 + tid;
    int r = p >> 4, c8 = p & 15;  // 64 rows x 16 short8 groups
    *(short8*)&inL[r][c8 * 8] = *(const short8*)(attno_b + (size_t)(row0 + r) * C_ + c8 * 8);
  }
  __syncthreads();
  int lane = tid & 63, w = tid >> 6, li = lane & 15, quad = lane >> 4;
  int r0 = w * 16;

  short8 aK[4];
#pragma unroll
  for (int k4 = 0; k4 < 4; ++k4) aK[k4] = *(const short8*)&inL[r0 + li][k4 * 32 + quad * 8];
  floatx4 acc[8];
#pragma unroll
  for (int t8 = 0; t8 < 8; ++t8) acc[t8] = (floatx4){0.f, 0.f, 0.f, 0.f};
#pragma unroll
  for (int t8 = 0; t8 < 8; ++t8) {
    const unsigned short* bp = aot + (size_t)(t8 * 16 + li) * 128 + quad * 8;
#pragma unroll
    for (int k4 = 0; k4 < 4; ++k4) {
      short8 bf = *(const short8*)(bp + k4 * 32);
      acc[t8] = __builtin_amdgcn_mfma_f32_16x16x32_bf16(aK[k4], bf, acc[t8], 0, 0, 0);
    }
  }
  float g2v[8], bl2v[8], abv[8];
#pragma unroll
  for (int t8 = 0; t8 < 8; ++t8) {
    int col = t8 * 16 + li;
    g2v[t8] = g2[col]; bl2v[t8] = bl2[col]; abv[t8] = ab[col];
  }
  float outv[8][4];
  float xkeep[8][4];
#pragma unroll
  for (int reg = 0; reg < 4; ++reg) {
    int row = row0 + r0 + quad * 4 + reg;
    float v[8], s = 0.f, s2 = 0.f;
#pragma unroll
    for (int t8 = 0; t8 < 8; ++t8) {
      float xv = x[(size_t)row * C_ + t8 * 16 + li];
      xkeep[t8][reg] = xv;
      v[t8] = acc[t8][reg] + abv[t8] + xv;
      s += v[t8]; s2 += v[t8] * v[t8];
    }
#pragma unroll
    for (int m = 1; m <= 8; m <<= 1) { s += __shfl_xor(s, m); s2 += __shfl_xor(s2, m); }
    float mu = s * (1.0f / C_);
    float var = s2 * (1.0f / C_) - mu * mu;
    float inv = rsqrtf(var + LNE);
#pragma unroll
    for (int t8 = 0; t8 < 8; ++t8) {
      int col = t8 * 16 + li;
      float ha = (v[t8] - mu) * inv * g2v[t8] + bl2v[t8];
      float ov = hl[(size_t)row * C_ + col] + ha;
      outv[t8][reg] = ov;
      inL[r0 + quad * 4 + reg][col] = f2bf_u(ov);
    }
  }

  short8 aK2[4];
#pragma unroll
  for (int k4 = 0; k4 < 4; ++k4) aK2[k4] = *(const short8*)&inL[r0 + li][k4 * 32 + quad * 8];
#pragma unroll
  for (int t8 = 0; t8 < 16; ++t8) {
    floatx4 a1 = {0.f, 0.f, 0.f, 0.f};
    const unsigned short* bp = w1t + (size_t)(t8 * 16 + li) * 128 + quad * 8;
#pragma unroll
    for (int k4 = 0; k4 < 4; ++k4) {
      short8 bf = *(const short8*)(bp + k4 * 32);
      a1 = __builtin_amdgcn_mfma_f32_16x16x32_bf16(aK2[k4], bf, a1, 0, 0, 0);
    }
    float bv = b1[t8 * 16 + li];
#pragma unroll
    for (int reg = 0; reg < 4; ++reg)
      hidL[r0 + quad * 4 + reg][t8 * 16 + li] = f2bf_u(gelu_tanh(a1[reg] + bv));
  }
  short8 aK3[8];
#pragma unroll
  for (int k4 = 0; k4 < 8; ++k4) aK3[k4] = *(const short8*)&hidL[r0 + li][k4 * 32 + quad * 8];
  floatx4 acc2[8];
#pragma unroll
  for (int t8 = 0; t8 < 8; ++t8) acc2[t8] = (floatx4){0.f, 0.f, 0.f, 0.f};
#pragma unroll
  for (int t8 = 0; t8 < 8; ++t8) {
    const unsigned short* bp = w2t + (size_t)(t8 * 16 + li) * 256 + quad * 8;
#pragma unroll
    for (int k4 = 0; k4 < 8; ++k4) {
      short8 bf = *(const short8*)(bp + k4 * 32);
      acc2[t8] = __builtin_amdgcn_mfma_f32_16x16x32_bf16(aK3[k4], bf, acc2[t8], 0, 0, 0);
    }
  }
  float g3v[8], bl3v[8], b2v[8];
#pragma unroll
  for (int t8 = 0; t8 < 8; ++t8) {
    int col = t8 * 16 + li;
    g3v[t8] = g3[col]; bl3v[t8] = bl3[col]; b2v[t8] = b2[col];
  }
#pragma unroll
  for (int reg = 0; reg < 4; ++reg) {
    int row = row0 + r0 + quad * 4 + reg;
    float v[8], s = 0.f, s2 = 0.f;
#pragma unroll
    for (int t8 = 0; t8 < 8; ++t8) {
      v[t8] = acc2[t8][reg] + b2v[t8] + outv[t8][reg];
      s += v[t8]; s2 += v[t8] * v[t8];
    }
#pragma unroll
    for (int m = 1; m <= 8; m <<= 1) { s += __shfl_xor(s, m); s2 += __shfl_xor(s2, m); }
    float mu = s * (1.0f / C_);
    float var = s2 * (1.0f / C_) - mu * mu;
    float inv = rsqrtf(var + LNE);
#pragma unroll
    for (int t8 = 0; t8 < 8; ++t8) {
      size_t idx = (size_t)row * C_ + t8 * 16 + li;
      x[idx] = xkeep[t8][reg] + (v[t8] - mu) * inv * g3v[t8] + bl3v[t8];
    }
  }
}

// ------------- FUSED post MLP + pool partials (atomic into gsum) -------------
__global__ void k_post_pool(float* __restrict__ x,
                            const float* __restrict__ w1, const float* __restrict__ b1,
                            const float* __restrict__ w2, const float* __restrict__ b2,
                            float* __restrict__ gsum) {
  __shared__ float inL[4][C_];
  __shared__ float hidL[4][C_];
  int t = threadIdx.x;
  int row0 = blockIdx.x * 4;
  float xv[4];
#pragma unroll
  for (int r = 0; r < 4; ++r) {
    size_t idx = (size_t)(row0 + r) * C_ + t;
    xv[r] = x[idx];
    inL[r][t] = xv[r];
  }
  __syncthreads();
  float acc[4];
  float bb = b1[t];
#pragma unroll
  for (int r = 0; r < 4; ++r) acc[r] = bb;
  for (int k = 0; k < C_; ++k) {
    float wv = w1[k * C_ + t];
#pragma unroll
    for (int r = 0; r < 4; ++r) acc[r] += inL[r][k] * wv;
  }
#pragma unroll
  for (int r = 0; r < 4; ++r) hidL[r][t] = fmaxf(acc[r], 0.0f);
  __syncthreads();
  float bb2 = b2[t];
#pragma unroll
  for (int r = 0; r < 4; ++r) acc[r] = bb2;
  for (int k = 0; k < C_; ++k) {
    float wv = w2[k * C_ + t];
#pragma unroll
    for (int r = 0; r < 4; ++r) acc[r] += hidL[r][k] * wv;
  }
  float local = 0.f;
#pragma unroll
  for (int r = 0; r < 4; ++r) {
    size_t idx = (size_t)(row0 + r) * C_ + t;
    float nv = xv[r] + acc[r];
    x[idx] = nv;
    local += nv;
  }
  int b = row0 / S_;
  atomicAdd(&gsum[b * C_ + t], local);
}

// ------------- readout (gsum holds SUM; divide by S) -------------
__global__ void k_readout(const float* __restrict__ gsum,
                          const float* __restrict__ w1, const float* __restrict__ b1,
                          const float* __restrict__ w2, const float* __restrict__ b2,
                          float* __restrict__ out) {
  __shared__ float gL[C_];
  __shared__ float red[C_];
  int t = threadIdx.x;
  int b = blockIdx.x;
  gL[t] = gsum[b * C_ + t] * (1.0f / S_);
  __syncthreads();
  float acc = b1[t];
  for (int k = 0; k < C_; ++k) acc += gL[k] * w1[k * C_ + t];
  float hid = fmaxf(acc, 0.0f);
  float part = hid * w2[t];
  float tot = block_sum128(part, red, t);
  if (t == 0) out[b] = tot + b2[0];
}

}  // namespace

extern "C" void kernel_launch(void* const* d_in, const int* in_sizes, int n_in,
                              void* d_out, int out_size, void* d_ws, size_t ws_size,
                              hipStream_t stream) {
  const float* in_x      = (const float*)d_in[0];
  const int*   edge_idx  = (const int*)d_in[1];
  const float* edge_attr = (const float*)d_in[3];
  const float* lap_pe    = (const float*)d_in[4];
  const float* node_w1 = (const float*)d_in[5];
  const float* node_b1 = (const float*)d_in[6];
  const float* node_w2 = (const float*)d_in[7];
  const float* node_b2 = (const float*)d_in[8];
  const float* edge_w1 = (const float*)d_in[9];
  const float* edge_b1 = (const float*)d_in[10];
  const float* edge_w2 = (const float*)d_in[11];
  const float* edge_b2 = (const float*)d_in[12];
  const float* eps     = (const float*)d_in[13];
  const float* gin_w1  = (const float*)d_in[14];
  const float* gin_b1  = (const float*)d_in[15];
  const float* gin_w2  = (const float*)d_in[16];
  const float* gin_b2  = (const float*)d_in[17];
  const float* elin_w  = (const float*)d_in[18];
  const float* elin_b  = (const float*)d_in[19];
  const float* aqkv_w  = (const float*)d_in[20];
  const float* aqkv_b  = (const float*)d_in[21];
  const float* aout_w  = (const float*)d_in[22];
  const float* aout_b  = (const float*)d_in[23];
  const float* mlp_w1  = (const float*)d_in[24];
  const float* mlp_b1  = (const float*)d_in[25];
  const float* mlp_w2  = (const float*)d_in[26];
  const float* mlp_b2  = (const float*)d_in[27];
  const float* ln1_g   = (const float*)d_in[28];
  const float* ln1_b   = (const float*)d_in[29];
  const float* ln2_g   = (const float*)d_in[30];
  const float* ln2_b   = (const float*)d_in[31];
  const float* ln3_g   = (const float*)d_in[32];
  const float* ln3_b   = (const float*)d_in[33];
  const float* post_w1 = (const float*)d_in[34];
  const float* post_b1 = (const float*)d_in[35];
  const float* post_w2 = (const float*)d_in[36];
  const float* post_b2 = (const float*)d_in[37];
  const float* ro_w1   = (const float*)d_in[38];
  const float* ro_b1   = (const float*)d_in[39];
  const float* ro_w2   = (const float*)d_in[40];
  const float* ro_b2   = (const float*)d_in[41];

  const int* src = edge_idx;
  const int* dst = edge_idx + E_;

  float* ws = (float*)d_ws;
  float* x     = ws;                                  // N*C
  unsigned short* qkvb = (unsigned short*)(x + (size_t)N_ * C_);  // N*384 bf16
  float* hl    = x + (size_t)N_ * C_ + (size_t)N_ * 192;          // N*C
  float* agg   = hl + (size_t)N_ * C_;                // N*C fp32; attno_b aliases (bf16)
  unsigned short* attno_b = (unsigned short*)agg;     // N*C bf16 (agg dead before attn)
  float* fb2   = agg + (size_t)N_ * C_;               // 512 floats
  unsigned short* fw2tb = (unsigned short*)(fb2 + 4 * C_);  // 65536 bf16
  unsigned short* wt = fw2tb + (size_t)4 * C_ * C_;   // 655360 bf16
  unsigned short* ew1tb = wt + 655360;                // 4096 bf16
  unsigned short* ea_b = ew1tb + 4096;                // E*16 bf16
  int* src_s   = (int*)(ea_b + (size_t)E_ * ED_);     // E
  int* dst_s   = src_s + E_;                          // E
  int* hist    = dst_s + E_;                          // 32768
  int* binStart = hist + 32768;                       // 32769
  int* perm    = binStart + 32769;                    // E
  float* gsum  = hl;                                  // alias

  float* out = (float*)d_out;

  dim3 blk(128);
  const size_t LWS = 163840;

  k_fuse_w<<<4 * (C_ + 1), blk, 0, stream>>>(edge_w2, edge_b2, elin_w, elin_b, fw2tb, fb2);
  k_prep<<<4 * 1152, blk, 0, stream>>>(gin_w1, gin_w2, aqkv_w, aout_w, mlp_w1, mlp_w2, wt);
  k_prep_ew1<<<128, 32, 0, stream>>>(edge_w1, ew1tb);
  k_zero<<<(32768 / 4 + 255) / 256, 256, 0, stream>>>((float4*)hist, 32768 / 4);
  k_count<<<E_ / 256, 256, 0, stream>>>(dst, hist);
  k_scan<<<1, 1024, 0, stream>>>(hist, binStart);
  k_scatter<<<E_ / 256, 256, 0, stream>>>(dst, hist, perm);
  k_gather_edges<<<E_ / 256, 256, 0, stream>>>(edge_attr, src, dst, perm,
                                               ea_b, src_s, dst_s);
  k_node_enc<<<N_ / 4, blk, 0, stream>>>(in_x, lap_pe, node_w1, node_b1, node_w2, node_b2, x);

  for (int i = 0; i < 4; ++i) {
    const unsigned short* wl = wt + (size_t)i * LWS;
    k_zero<<<(N_ * C_ / 4 + 255) / 256, 256, 0, stream>>>((float4*)agg, N_ * C_ / 4);
    k_edge_mfma<<<E_ / 64, 256, 0, stream>>>(ea_b, x, src_s, dst_s,
                                             ew1tb, edge_b1,
                                             fw2tb + (size_t)i * C_ * C_, fb2 + i * C_, agg);
    k_ginqkv<<<N_ / 64, 256, 0, stream>>>(x, agg,
                                          wl + 0, gin_b1 + i * C_,
                                          wl + 16384, gin_b2 + i * C_,
                                          ln1_g + i * C_, ln1_b + i * C_, eps, i, hl,
                                          wl + 32768, aqkv_b + i * 384, qkvb);
    k_attn_mfma<<<B_ * 4 * 16, 256, 0, stream>>>(qkvb, attno_b);
    k_aoffn<<<N_ / 64, 256, 0, stream>>>(attno_b, x, hl,
                                         wl + 81920, aout_b + i * C_,
                                         ln2_g + i * C_, ln2_b + i * C_,
                                         wl + 98304, mlp_b1 + i * 256,
                                         wl + 131072, mlp_b2 + i * C_,
                                         ln3_g + i * C_, ln3_b + i * C_);
  }

  k_zero<<<(B_ * C_ / 4 + 255) / 256, 256, 0, stream>>>((float4*)gsum, B_ * C_ / 4);
  k_post_pool<<<N_ / 4, blk, 0, stream>>>(x, post_w1, post_b1, post_w2, post_b2, gsum);
  k_readout<<<B_, blk, 0, stream>>>(gsum, ro_w1, ro_b1, ro_w2, ro_b2, out);
}

// Round 14
// 1235.693 us; speedup vs baseline: 1.0268x; 1.0268x over previous
//
#include <hip/hip_runtime.h>
#include <math.h>

namespace {

constexpr int N_  = 32768;   // nodes
constexpr int S_  = 1024;    // nodes per graph
constexpr int B_  = 32;      // graphs
constexpr int E_  = 262144;  // edges
constexpr int C_  = 128;     // hidden
constexpr int ND_ = 64;
constexpr int PE_ = 16;
constexpr int ED_ = 16;
constexpr float LNE = 1e-5f;

typedef __attribute__((ext_vector_type(8))) short short8;
typedef __attribute__((ext_vector_type(4))) float floatx4;

__device__ inline float gelu_tanh(float v) {
  const float c = 0.7978845608028654f;
  return 0.5f * v * (1.0f + tanhf(c * (v + 0.044715f * v * v * v)));
}

__device__ inline unsigned short f2bf_u(float f) {
  unsigned u = __float_as_uint(f);
  u += 0x7fff + ((u >> 16) & 1);
  return (unsigned short)(u >> 16);
}

__device__ inline float bf2f(unsigned short v) {
  return __uint_as_float(((unsigned)v) << 16);
}

__device__ inline float block_sum128(float v, float* red, int t) {
  red[t] = v;
  __syncthreads();
#pragma unroll
  for (int off = 64; off > 0; off >>= 1) {
    if (t < off) red[t] += red[t + off];
    __syncthreads();
  }
  float r = red[0];
  __syncthreads();
  return r;
}

// ---------------- zero (graph-capture-safe memset) ----------------
__global__ void k_zero(float4* __restrict__ p, int n4) {
  int i = blockIdx.x * 256 + threadIdx.x;
  if (i < n4) p[i] = make_float4(0.f, 0.f, 0.f, 0.f);
}

// ---------------- counting sort by dst ----------------
__global__ void k_count(const int* __restrict__ dst, int* __restrict__ hist) {
  int e = blockIdx.x * 256 + threadIdx.x;
  if (e < E_) atomicAdd(&hist[dst[e]], 1);
}

__global__ __launch_bounds__(1024) void k_scan(int* __restrict__ hist, int* __restrict__ binStart) {
  __shared__ int sums[1024];
  int t = threadIdx.x;
  int base = t * 32;
  int loc[32];
  int s = 0;
#pragma unroll
  for (int i = 0; i < 32; ++i) { loc[i] = s; s += hist[base + i]; }
  sums[t] = s;
  __syncthreads();
  for (int off = 1; off < 1024; off <<= 1) {
    int v = (t >= off) ? sums[t - off] : 0;
    __syncthreads();
    sums[t] += v;
    __syncthreads();
  }
  int excl = sums[t] - s;
#pragma unroll
  for (int i = 0; i < 32; ++i) {
    int v = excl + loc[i];
    binStart[base + i] = v;
    hist[base + i] = v;  // cursor (in-place)
  }
  if (t == 1023) binStart[32768] = sums[1023];
}

__global__ void k_scatter(const int* __restrict__ dst, int* __restrict__ cursor,
                          int* __restrict__ perm) {
  int e = blockIdx.x * 256 + threadIdx.x;
  if (e < E_) {
    int p = atomicAdd(&cursor[dst[e]], 1);
    perm[p] = e;
  }
}

// gather edge data into sorted order, bf16 (coalesced writes; one-time)
__global__ void k_gather_edges(const float* __restrict__ ea, const int* __restrict__ src,
                               const int* __restrict__ dst, const int* __restrict__ perm,
                               unsigned short* __restrict__ ea_b, int* __restrict__ src_s,
                               int* __restrict__ dst_s) {
  int p = blockIdx.x * 256 + threadIdx.x;  // edge slot
  if (p >= E_) return;
  int e = perm[p];
  const float4* s = (const float4*)(ea + (size_t)e * ED_);
  unsigned short* d = ea_b + (size_t)p * ED_;
#pragma unroll
  for (int i = 0; i < 4; ++i) {
    float4 v = s[i];
    ushort4 u;
    u.x = f2bf_u(v.x); u.y = f2bf_u(v.y); u.z = f2bf_u(v.z); u.w = f2bf_u(v.w);
    *(ushort4*)(d + i * 4) = u;
  }
  src_s[p] = src[e];
  dst_s[p] = dst[e];
}

// ---------------- fold edge_w2 into elin; emit TRANSPOSED bf16 weight ----------------
__global__ void k_fuse_w(const float* __restrict__ w2, const float* __restrict__ b2,
                         const float* __restrict__ elin_w, const float* __restrict__ elin_b,
                         unsigned short* __restrict__ fw2t, float* __restrict__ fb2) {
  int t = threadIdx.x;
  int bid = blockIdx.x;
  int layer = bid / (C_ + 1);
  int k = bid % (C_ + 1);
  const float* el = elin_w + (size_t)layer * C_ * C_;
  if (k < C_) {
    float a = 0.0f;
    for (int m = 0; m < C_; ++m) a += w2[k * C_ + m] * el[m * C_ + t];
    fw2t[(size_t)layer * C_ * C_ + t * C_ + k] = f2bf_u(a);
  } else {
    float a = elin_b[layer * C_ + t];
    for (int m = 0; m < C_; ++m) a += b2[m] * el[m * C_ + t];
    fb2[layer * C_ + t] = a;
  }
}

// ---------------- prep edge_w1 transposed bf16 with zero-padded K (16->32) ----------------
__global__ void k_prep_ew1(const float* __restrict__ ew1, unsigned short* __restrict__ ew1t) {
  int n = blockIdx.x;        // 128
  int k = threadIdx.x;       // 32
  ew1t[n * 32 + k] = (k < ED_) ? f2bf_u(ew1[k * C_ + n]) : (unsigned short)0;
}

// ---------------- prep: bf16-transpose all node-path weights ----------------
__global__ void k_prep(const float* __restrict__ gin_w1, const float* __restrict__ gin_w2,
                       const float* __restrict__ aqkv_w, const float* __restrict__ aout_w,
                       const float* __restrict__ mlp_w1, const float* __restrict__ mlp_w2,
                       unsigned short* __restrict__ wt) {
  int t = threadIdx.x;
  int bid = blockIdx.x;
  int l = bid / 1152;
  int r = bid % 1152;
  unsigned short* base = wt + (size_t)l * 163840;
  if (r < 128) {
    base[r * 128 + t] = f2bf_u(gin_w1[(size_t)l * 16384 + t * 128 + r]);
  } else if (r < 256) {
    int n = r - 128;
    base[16384 + n * 128 + t] = f2bf_u(gin_w2[(size_t)l * 16384 + t * 128 + n]);
  } else if (r < 640) {
    int n = r - 256;
    base[32768 + n * 128 + t] = f2bf_u(aqkv_w[(size_t)l * 49152 + t * 384 + n]);
  } else if (r < 768) {
    int n = r - 640;
    base[81920 + n * 128 + t] = f2bf_u(aout_w[(size_t)l * 16384 + t * 128 + n]);
  } else if (r < 1024) {
    int n = r - 768;
    base[98304 + n * 128 + t] = f2bf_u(mlp_w1[(size_t)l * 32768 + t * 256 + n]);
  } else {
    int n = r - 1024;
    base[131072 + n * 256 + t]       = f2bf_u(mlp_w2[(size_t)l * 32768 + t * 128 + n]);
    base[131072 + n * 256 + 128 + t] = f2bf_u(mlp_w2[(size_t)l * 32768 + (t + 128) * 128 + n]);
  }
}

// ---------------- node encoder (scalar fp32) ----------------
__global__ void k_node_enc(const float* __restrict__ xin, const float* __restrict__ pe,
                           const float* __restrict__ w1, const float* __restrict__ b1,
                           const float* __restrict__ w2, const float* __restrict__ b2,
                           float* __restrict__ xout) {
  __shared__ float inL[4][80];
  __shared__ float hidL[4][C_];
  int t = threadIdx.x;
  int row0 = blockIdx.x * 4;
#pragma unroll
  for (int r = 0; r < 4; ++r) {
    int row = row0 + r;
    if (t < ND_) inL[r][t] = xin[(size_t)row * ND_ + t];
    else if (t < 80) inL[r][t] = pe[(size_t)row * PE_ + (t - ND_)];
  }
  __syncthreads();
  float acc[4];
  float bb = b1[t];
#pragma unroll
  for (int r = 0; r < 4; ++r) acc[r] = bb;
  for (int k = 0; k < 80; ++k) {
    float wv = w1[k * C_ + t];
#pragma unroll
    for (int r = 0; r < 4; ++r) acc[r] += inL[r][k] * wv;
  }
#pragma unroll
  for (int r = 0; r < 4; ++r) hidL[r][t] = fmaxf(acc[r], 0.0f);
  __syncthreads();
  float bb2 = b2[t];
#pragma unroll
  for (int r = 0; r < 4; ++r) acc[r] = bb2;
  for (int k = 0; k < C_; ++k) {
    float wv = w2[k * C_ + t];
#pragma unroll
    for (int r = 0; r < 4; ++r) acc[r] += hidL[r][k] * wv;
  }
#pragma unroll
  for (int r = 0; r < 4; ++r) xout[(size_t)(row0 + r) * C_ + t] = acc[r];
}

// ------------- MFMA edge pipeline v4 (r12-verified) -------------
__global__ __launch_bounds__(256) void k_edge_mfma(
    const unsigned short* __restrict__ ea_b, const float* __restrict__ x,
    const int* __restrict__ src_s, const int* __restrict__ dst_s,
    const unsigned short* __restrict__ ew1t, const float* __restrict__ eb1,
    const unsigned short* __restrict__ fw2t, const float* __restrict__ fb2,
    float* __restrict__ agg) {
  __shared__ unsigned short eaL[64][32];
  __shared__ unsigned short buf[64][136];
  __shared__ unsigned short xrL[64][136];
  __shared__ int srcL[64], dstL[64];
  int tid = threadIdx.x;
  int e0 = blockIdx.x * 64;

  if (tid < 64) { srcL[tid] = src_s[e0 + tid]; dstL[tid] = dst_s[e0 + tid]; }
  if (tid < 128) {
    int r = tid >> 1, hf = tid & 1;
    *(short8*)&eaL[r][hf * 8] = *(const short8*)(ea_b + (size_t)(e0 + r) * ED_ + hf * 8);
  } else {
    int r = (tid - 128) >> 1, hf = (tid - 128) & 1;
    short8 z = {0, 0, 0, 0, 0, 0, 0, 0};
    *(short8*)&eaL[r][16 + hf * 8] = z;
  }
  __syncthreads();

  float4 xv[8];
#pragma unroll
  for (int it = 0; it < 8; ++it) {
    int idx = it * 256 + tid;
    int r = idx >> 5, c4 = idx & 31;
    xv[it] = *(const float4*)(x + (size_t)srcL[r] * C_ + c4 * 4);
  }

  int lane = tid & 63;
  int w = tid >> 6;
  int li = lane & 15;
  int quad = lane >> 4;
  int r0 = w * 16;

  short8 aE = *(const short8*)&eaL[r0 + li][quad * 8];
#pragma unroll
  for (int t8 = 0; t8 < 8; ++t8) {
    short8 bE = *(const short8*)(ew1t + (size_t)(t8 * 16 + li) * 32 + quad * 8);
    floatx4 z = {0.f, 0.f, 0.f, 0.f};
    floatx4 h = __builtin_amdgcn_mfma_f32_16x16x32_bf16(aE, bE, z, 0, 0, 0);
    float bv = eb1[t8 * 16 + li];
#pragma unroll
    for (int reg = 0; reg < 4; ++reg)
      buf[r0 + quad * 4 + reg][t8 * 16 + li] = f2bf_u(fmaxf(h[reg] + bv, 0.f));
  }

#pragma unroll
  for (int it = 0; it < 8; ++it) {
    int idx = it * 256 + tid;
    int r = idx >> 5, c4 = idx & 31;
    ushort4 u;
    u.x = f2bf_u(xv[it].x); u.y = f2bf_u(xv[it].y);
    u.z = f2bf_u(xv[it].z); u.w = f2bf_u(xv[it].w);
    *(ushort4*)&xrL[r][c4 * 4] = u;
  }
  __syncthreads();

  short8 aK[4];
#pragma unroll
  for (int k4 = 0; k4 < 4; ++k4)
    aK[k4] = *(const short8*)&buf[r0 + li][k4 * 32 + quad * 8];

  float fbv[8];
#pragma unroll
  for (int t8 = 0; t8 < 8; ++t8) fbv[t8] = fb2[t8 * 16 + li];

#pragma unroll
  for (int t8 = 0; t8 < 8; ++t8) {
    floatx4 acc = {0.f, 0.f, 0.f, 0.f};
    const unsigned short* bp = fw2t + (size_t)(t8 * 16 + li) * C_ + quad * 8;
#pragma unroll
    for (int k4 = 0; k4 < 4; ++k4) {
      short8 bf = *(const short8*)(bp + k4 * 32);
      acc = __builtin_amdgcn_mfma_f32_16x16x32_bf16(aK[k4], bf, acc, 0, 0, 0);
    }
    int n = t8 * 16 + li;
#pragma unroll
    for (int reg = 0; reg < 4; ++reg) {
      int cr = r0 + quad * 4 + reg;
      float v = fmaxf(acc[reg] + fbv[t8] + bf2f(xrL[cr][n]), 0.0f);
      buf[cr][n] = f2bf_u(v);
    }
  }
  __syncthreads();

  {
    int col = tid & 127;
    int rbase = (tid >> 7) * 32;
    float run = bf2f(buf[rbase][col]);
    int cur = dstL[rbase];
    for (int r = 1; r < 32; ++r) {
      int rr = rbase + r;
      int d = dstL[rr];
      float v = bf2f(buf[rr][col]);
      if (d != cur) {
        atomicAdd(&agg[(size_t)cur * C_ + col], run);
        run = v; cur = d;
      } else {
        run += v;
      }
    }
    atomicAdd(&agg[(size_t)cur * C_ + col], run);
  }
}

// ------------- FUSED GIN + QKV (LN1 residual from LDS; r13 part kept) -------------
__global__ __launch_bounds__(256) void k_ginqkv(
    const float* __restrict__ x, const float* __restrict__ agg,
    const unsigned short* __restrict__ w1t, const float* __restrict__ b1,
    const unsigned short* __restrict__ w2t, const float* __restrict__ b2,
    const float* __restrict__ g, const float* __restrict__ bln,
    const float* __restrict__ epsarr, int layer, float* __restrict__ hl,
    const unsigned short* __restrict__ qkvt, const float* __restrict__ qb,
    unsigned short* __restrict__ qkvb) {
  __shared__ unsigned short inL[64][136];
  __shared__ unsigned short xbL[64][136];
  int tid = threadIdx.x;
  int row0 = blockIdx.x * 64;
  float epsv = 1.0f + epsarr[layer];
#pragma unroll
  for (int i = 0; i < 8; ++i) {
    int p = i * 256 + tid;
    int r = p >> 5, c4 = p & 31;
    float4 xa = *(const float4*)(x + (size_t)(row0 + r) * C_ + c4 * 4);
    float4 ag = *(const float4*)(agg + (size_t)(row0 + r) * C_ + c4 * 4);
    ushort4 ux;
    ux.x = f2bf_u(xa.x); ux.y = f2bf_u(xa.y); ux.z = f2bf_u(xa.z); ux.w = f2bf_u(xa.w);
    *(ushort4*)&xbL[r][c4 * 4] = ux;
    ushort4 u;
    u.x = f2bf_u(epsv * xa.x + ag.x);
    u.y = f2bf_u(epsv * xa.y + ag.y);
    u.z = f2bf_u(epsv * xa.z + ag.z);
    u.w = f2bf_u(epsv * xa.w + ag.w);
    *(ushort4*)&inL[r][c4 * 4] = u;
  }
  __syncthreads();
  int lane = tid & 63, w = tid >> 6, li = lane & 15, quad = lane >> 4;
  int r0 = w * 16;

  short8 aK[4];
#pragma unroll
  for (int k4 = 0; k4 < 4; ++k4) aK[k4] = *(const short8*)&inL[r0 + li][k4 * 32 + quad * 8];
#pragma unroll
  for (int t8 = 0; t8 < 8; ++t8) {
    floatx4 acc = {0.f, 0.f, 0.f, 0.f};
    const unsigned short* bp = w1t + (size_t)(t8 * 16 + li) * 128 + quad * 8;
#pragma unroll
    for (int k4 = 0; k4 < 4; ++k4) {
      short8 bf = *(const short8*)(bp + k4 * 32);
      acc = __builtin_amdgcn_mfma_f32_16x16x32_bf16(aK[k4], bf, acc, 0, 0, 0);
    }
    float bv = b1[t8 * 16 + li];
#pragma unroll
    for (int reg = 0; reg < 4; ++reg)
      inL[r0 + quad * 4 + reg][t8 * 16 + li] = f2bf_u(fmaxf(acc[reg] + bv, 0.f));
  }
  short8 aK2[4];
#pragma unroll
  for (int k4 = 0; k4 < 4; ++k4) aK2[k4] = *(const short8*)&inL[r0 + li][k4 * 32 + quad * 8];
  floatx4 acc2[8];
#pragma unroll
  for (int t8 = 0; t8 < 8; ++t8) acc2[t8] = (floatx4){0.f, 0.f, 0.f, 0.f};
#pragma unroll
  for (int t8 = 0; t8 < 8; ++t8) {
    const unsigned short* bp = w2t + (size_t)(t8 * 16 + li) * 128 + quad * 8;
#pragma unroll
    for (int k4 = 0; k4 < 4; ++k4) {
      short8 bf = *(const short8*)(bp + k4 * 32);
      acc2[t8] = __builtin_amdgcn_mfma_f32_16x16x32_bf16(aK2[k4], bf, acc2[t8], 0, 0, 0);
    }
  }
  float gv[8], blv[8], b2v[8];
#pragma unroll
  for (int t8 = 0; t8 < 8; ++t8) {
    int col = t8 * 16 + li;
    gv[t8] = g[col]; blv[t8] = bln[col]; b2v[t8] = b2[col];
  }
#pragma unroll
  for (int reg = 0; reg < 4; ++reg) {
    int row = row0 + r0 + quad * 4 + reg;
    int lr = r0 + quad * 4 + reg;
    float v[8], s = 0.f, s2 = 0.f;
#pragma unroll
    for (int t8 = 0; t8 < 8; ++t8) {
      float xv = bf2f(xbL[lr][t8 * 16 + li]);
      v[t8] = acc2[t8][reg] + b2v[t8] + xv;
      s += v[t8]; s2 += v[t8] * v[t8];
    }
#pragma unroll
    for (int m = 1; m <= 8; m <<= 1) { s += __shfl_xor(s, m); s2 += __shfl_xor(s2, m); }
    float mu = s * (1.0f / C_);
    float var = s2 * (1.0f / C_) - mu * mu;
    float inv = rsqrtf(var + LNE);
#pragma unroll
    for (int t8 = 0; t8 < 8; ++t8)
      hl[(size_t)row * C_ + t8 * 16 + li] = (v[t8] - mu) * inv * gv[t8] + blv[t8];
  }

  short8 aQ[4];
#pragma unroll
  for (int k4 = 0; k4 < 4; ++k4) aQ[k4] = *(const short8*)&xbL[r0 + li][k4 * 32 + quad * 8];
#pragma unroll
  for (int t8 = 0; t8 < 24; ++t8) {
    floatx4 acc = {0.f, 0.f, 0.f, 0.f};
    const unsigned short* bp = qkvt + (size_t)(t8 * 16 + li) * 128 + quad * 8;
#pragma unroll
    for (int k4 = 0; k4 < 4; ++k4) {
      short8 bf = *(const short8*)(bp + k4 * 32);
      acc = __builtin_amdgcn_mfma_f32_16x16x32_bf16(aQ[k4], bf, acc, 0, 0, 0);
    }
    int col = t8 * 16 + li;
    float bv = qb[col];
#pragma unroll
    for (int reg = 0; reg < 4; ++reg) {
      int row = row0 + r0 + quad * 4 + reg;
      qkvb[(size_t)row * 384 + col] = f2bf_u(acc[reg] + bv);
    }
  }
}

// ------------- MFMA flash attention v3 -> bf16 output -------------
__global__ __launch_bounds__(256) void k_attn_mfma(const unsigned short* __restrict__ qkvb,
                                                   unsigned short* __restrict__ attno_b) {
  __shared__ unsigned short kL[2][32][40];
  __shared__ unsigned short vT[2][32][40];
  __shared__ unsigned short pL[4][16][40];
  int tid = threadIdx.x;
  int lane = tid & 63;
  int w = tid >> 6;
  int li = lane & 15;
  int quad = lane >> 4;
  int bid = blockIdx.x;
  int b = (bid & 7) * 4 + ((bid >> 3) & 3);
  int rest = bid >> 5;
  int h = rest & 3;
  int qt = rest >> 2;
  int qbase = b * S_ + qt * 64 + w * 16;

  short8 qA = *(const short8*)(qkvb + (size_t)(qbase + li) * 384 + h * 32 + quad * 8);

  floatx4 o0 = {0.f, 0.f, 0.f, 0.f}, o1 = {0.f, 0.f, 0.f, 0.f};
  float lsum[4] = {0.f, 0.f, 0.f, 0.f};
  const float scale = 0.17677669529663687f;

  int half = tid >> 7;
  int tt = tid & 127;
  int j = tt >> 2;
  int seg = tt & 3;
  int vcol = (((j >> 3) ^ seg) & 3) * 8 + (j & 7);
  int vg0 = ((quad ^ (li >> 3)) & 3) * 8;
  int vg1 = ((quad ^ (2 + (li >> 3))) & 3) * 8;

  const unsigned short* pbase = qkvb + (half ? 256 : 128) + h * 32 + seg * 8;

  short8 val = *(const short8*)(pbase + (size_t)(b * S_ + 0 * 32 + j) * 384);

  for (int kc = 0; kc < 32; ++kc) {
    int buf = kc & 1;
    if (half == 0) {
      *(short8*)&kL[buf][j][seg * 8] = val;
    } else {
#pragma unroll
      for (int i = 0; i < 8; ++i) vT[buf][seg * 8 + i][vcol] = (unsigned short)val[i];
    }
    __syncthreads();
    if (kc < 31)
      val = *(const short8*)(pbase + (size_t)(b * S_ + (kc + 1) * 32 + j) * 384);
    short8 kB0 = *(const short8*)&kL[buf][li][quad * 8];
    short8 kB1 = *(const short8*)&kL[buf][16 + li][quad * 8];
    floatx4 z = {0.f, 0.f, 0.f, 0.f};
    floatx4 s0 = __builtin_amdgcn_mfma_f32_16x16x32_bf16(qA, kB0, z, 0, 0, 0);
    floatx4 s1 = __builtin_amdgcn_mfma_f32_16x16x32_bf16(qA, kB1, z, 0, 0, 0);
#pragma unroll
    for (int r = 0; r < 4; ++r) {
      float p0 = __expf(s0[r] * scale);
      float p1 = __expf(s1[r] * scale);
      lsum[r] += p0 + p1;
      pL[w][quad * 4 + r][li] = f2bf_u(p0);
      pL[w][quad * 4 + r][16 + li] = f2bf_u(p1);
    }
    short8 pA  = *(const short8*)&pL[w][li][quad * 8];
    short8 vB0 = *(const short8*)&vT[buf][li][vg0];
    short8 vB1 = *(const short8*)&vT[buf][16 + li][vg1];
    o0 = __builtin_amdgcn_mfma_f32_16x16x32_bf16(pA, vB0, o0, 0, 0, 0);
    o1 = __builtin_amdgcn_mfma_f32_16x16x32_bf16(pA, vB1, o1, 0, 0, 0);
  }
#pragma unroll
  for (int r = 0; r < 4; ++r) {
    float l = lsum[r];
#pragma unroll
    for (int msk = 1; msk <= 8; msk <<= 1) l += __shfl_xor(l, msk);
    float inv = 1.0f / l;
    size_t row = (size_t)(qbase + quad * 4 + r);
    attno_b[row * C_ + h * 32 + li] = f2bf_u(o0[r] * inv);
    attno_b[row * C_ + h * 32 + 16 + li] = f2bf_u(o1[r] * inv);
  }
}

// ------------- FUSED attn-out-proj + LN2 + FFN + LN3 (r12 epilogue) + agg zero tail ------
__global__ __launch_bounds__(256) void k_aoffn(
    const unsigned short* __restrict__ attno_b, float* __restrict__ x,
    const float* __restrict__ hl,
    const unsigned short* __restrict__ aot, const float* __restrict__ ab,
    const float* __restrict__ g2, const float* __restrict__ bl2,
    const unsigned short* __restrict__ w1t, const float* __restrict__ b1,
    const unsigned short* __restrict__ w2t, const float* __restrict__ b2,
    const float* __restrict__ g3, const float* __restrict__ bl3,
    float* __restrict__ agg) {
  __shared__ unsigned short inL[64][136];
  __shared__ unsigned short hidL[64][264];
  int tid = threadIdx.x;
  int row0 = blockIdx.x * 64;
#pragma unroll
  for (int i = 0; i < 4; ++i) {
    int p = i * 256 + tid;
    int r = p >> 4, c8 = p & 15;
    *(short8*)&inL[r][c8 * 8] = *(const short8*)(attno_b + (size_t)(row0 + r) * C_ + c8 * 8);
  }
  __syncthreads();
  int lane = tid & 63, w = tid >> 6, li = lane & 15, quad = lane >> 4;
  int r0 = w * 16;

  short8 aK[4];
#pragma unroll
  for (int k4 = 0; k4 < 4; ++k4) aK[k4] = *(const short8*)&inL[r0 + li][k4 * 32 + quad * 8];
  floatx4 acc[8];
#pragma unroll
  for (int t8 = 0; t8 < 8; ++t8) acc[t8] = (floatx4){0.f, 0.f, 0.f, 0.f};
#pragma unroll
  for (int t8 = 0; t8 < 8; ++t8) {
    const unsigned short* bp = aot + (size_t)(t8 * 16 + li) * 128 + quad * 8;
#pragma unroll
    for (int k4 = 0; k4 < 4; ++k4) {
      short8 bf = *(const short8*)(bp + k4 * 32);
      acc[t8] = __builtin_amdgcn_mfma_f32_16x16x32_bf16(aK[k4], bf, acc[t8], 0, 0, 0);
    }
  }
  float g2v[8], bl2v[8], abv[8];
#pragma unroll
  for (int t8 = 0; t8 < 8; ++t8) {
    int col = t8 * 16 + li;
    g2v[t8] = g2[col]; bl2v[t8] = bl2[col]; abv[t8] = ab[col];
  }
  float outv[8][4];
#pragma unroll
  for (int reg = 0; reg < 4; ++reg) {
    int row = row0 + r0 + quad * 4 + reg;
    float v[8], s = 0.f, s2 = 0.f;
#pragma unroll
    for (int t8 = 0; t8 < 8; ++t8) {
      float xv = x[(size_t)row * C_ + t8 * 16 + li];
      v[t8] = acc[t8][reg] + abv[t8] + xv;
      s += v[t8]; s2 += v[t8] * v[t8];
    }
#pragma unroll
    for (int m = 1; m <= 8; m <<= 1) { s += __shfl_xor(s, m); s2 += __shfl_xor(s2, m); }
    float mu = s * (1.0f / C_);
    float var = s2 * (1.0f / C_) - mu * mu;
    float inv = rsqrtf(var + LNE);
#pragma unroll
    for (int t8 = 0; t8 < 8; ++t8) {
      int col = t8 * 16 + li;
      float ha = (v[t8] - mu) * inv * g2v[t8] + bl2v[t8];
      float ov = hl[(size_t)row * C_ + col] + ha;
      outv[t8][reg] = ov;
      inL[r0 + quad * 4 + reg][col] = f2bf_u(ov);
    }
  }

  short8 aK2[4];
#pragma unroll
  for (int k4 = 0; k4 < 4; ++k4) aK2[k4] = *(const short8*)&inL[r0 + li][k4 * 32 + quad * 8];
#pragma unroll
  for (int t8 = 0; t8 < 16; ++t8) {
    floatx4 a1 = {0.f, 0.f, 0.f, 0.f};
    const unsigned short* bp = w1t + (size_t)(t8 * 16 + li) * 128 + quad * 8;
#pragma unroll
    for (int k4 = 0; k4 < 4; ++k4) {
      short8 bf = *(const short8*)(bp + k4 * 32);
      a1 = __builtin_amdgcn_mfma_f32_16x16x32_bf16(aK2[k4], bf, a1, 0, 0, 0);
    }
    float bv = b1[t8 * 16 + li];
#pragma unroll
    for (int reg = 0; reg < 4; ++reg)
      hidL[r0 + quad * 4 + reg][t8 * 16 + li] = f2bf_u(gelu_tanh(a1[reg] + bv));
  }
  short8 aK3[8];
#pragma unroll
  for (int k4 = 0; k4 < 8; ++k4) aK3[k4] = *(const short8*)&hidL[r0 + li][k4 * 32 + quad * 8];
  floatx4 acc2[8];
#pragma unroll
  for (int t8 = 0; t8 < 8; ++t8) acc2[t8] = (floatx4){0.f, 0.f, 0.f, 0.f};
#pragma unroll
  for (int t8 = 0; t8 < 8; ++t8) {
    const unsigned short* bp = w2t + (size_t)(t8 * 16 + li) * 256 + quad * 8;
#pragma unroll
    for (int k4 = 0; k4 < 8; ++k4) {
      short8 bf = *(const short8*)(bp + k4 * 32);
      acc2[t8] = __builtin_amdgcn_mfma_f32_16x16x32_bf16(aK3[k4], bf, acc2[t8], 0, 0, 0);
    }
  }
  float g3v[8], bl3v[8], b2v[8];
#pragma unroll
  for (int t8 = 0; t8 < 8; ++t8) {
    int col = t8 * 16 + li;
    g3v[t8] = g3[col]; bl3v[t8] = bl3[col]; b2v[t8] = b2[col];
  }
#pragma unroll
  for (int reg = 0; reg < 4; ++reg) {
    int row = row0 + r0 + quad * 4 + reg;
    float v[8], s = 0.f, s2 = 0.f;
#pragma unroll
    for (int t8 = 0; t8 < 8; ++t8) {
      v[t8] = acc2[t8][reg] + b2v[t8] + outv[t8][reg];
      s += v[t8]; s2 += v[t8] * v[t8];
    }
#pragma unroll
    for (int m = 1; m <= 8; m <<= 1) { s += __shfl_xor(s, m); s2 += __shfl_xor(s2, m); }
    float mu = s * (1.0f / C_);
    float var = s2 * (1.0f / C_) - mu * mu;
    float inv = rsqrtf(var + LNE);
#pragma unroll
    for (int t8 = 0; t8 < 8; ++t8) {
      size_t idx = (size_t)row * C_ + t8 * 16 + li;
      x[idx] = x[idx] + (v[t8] - mu) * inv * g3v[t8] + bl3v[t8];
    }
  }

  // zero this block's agg rows for the next layer (overlapped memset; agg un-aliased)
  float4 z4 = make_float4(0.f, 0.f, 0.f, 0.f);
#pragma unroll
  for (int i = 0; i < 8; ++i) {
    int p = i * 256 + tid;
    int r = p >> 5, c4 = p & 31;
    *(float4*)(agg + (size_t)(row0 + r) * C_ + c4 * 4) = z4;
  }
}

// ------------- FUSED post MLP + pool partials (atomic into gsum) -------------
__global__ void k_post_pool(float* __restrict__ x,
                            const float* __restrict__ w1, const float* __restrict__ b1,
                            const float* __restrict__ w2, const float* __restrict__ b2,
                            float* __restrict__ gsum) {
  __shared__ float inL[4][C_];
  __shared__ float hidL[4][C_];
  int t = threadIdx.x;
  int row0 = blockIdx.x * 4;
  float xv[4];
#pragma unroll
  for (int r = 0; r < 4; ++r) {
    size_t idx = (size_t)(row0 + r) * C_ + t;
    xv[r] = x[idx];
    inL[r][t] = xv[r];
  }
  __syncthreads();
  float acc[4];
  float bb = b1[t];
#pragma unroll
  for (int r = 0; r < 4; ++r) acc[r] = bb;
  for (int k = 0; k < C_; ++k) {
    float wv = w1[k * C_ + t];
#pragma unroll
    for (int r = 0; r < 4; ++r) acc[r] += inL[r][k] * wv;
  }
#pragma unroll
  for (int r = 0; r < 4; ++r) hidL[r][t] = fmaxf(acc[r], 0.0f);
  __syncthreads();
  float bb2 = b2[t];
#pragma unroll
  for (int r = 0; r < 4; ++r) acc[r] = bb2;
  for (int k = 0; k < C_; ++k) {
    float wv = w2[k * C_ + t];
#pragma unroll
    for (int r = 0; r < 4; ++r) acc[r] += hidL[r][k] * wv;
  }
  float local = 0.f;
#pragma unroll
  for (int r = 0; r < 4; ++r) {
    size_t idx = (size_t)(row0 + r) * C_ + t;
    float nv = xv[r] + acc[r];
    x[idx] = nv;
    local += nv;
  }
  int b = row0 / S_;
  atomicAdd(&gsum[b * C_ + t], local);
}

// ------------- readout (gsum holds SUM; divide by S) -------------
__global__ void k_readout(const float* __restrict__ gsum,
                          const float* __restrict__ w1, const float* __restrict__ b1,
                          const float* __restrict__ w2, const float* __restrict__ b2,
                          float* __restrict__ out) {
  __shared__ float gL[C_];
  __shared__ float red[C_];
  int t = threadIdx.x;
  int b = blockIdx.x;
  gL[t] = gsum[b * C_ + t] * (1.0f / S_);
  __syncthreads();
  float acc = b1[t];
  for (int k = 0; k < C_; ++k) acc += gL[k] * w1[k * C_ + t];
  float hid = fmaxf(acc, 0.0f);
  float part = hid * w2[t];
  float tot = block_sum128(part, red, t);
  if (t == 0) out[b] = tot + b2[0];
}

}  // namespace

extern "C" void kernel_launch(void* const* d_in, const int* in_sizes, int n_in,
                              void* d_out, int out_size, void* d_ws, size_t ws_size,
                              hipStream_t stream) {
  const float* in_x      = (const float*)d_in[0];
  const int*   edge_idx  = (const int*)d_in[1];
  const float* edge_attr = (const float*)d_in[3];
  const float* lap_pe    = (const float*)d_in[4];
  const float* node_w1 = (const float*)d_in[5];
  const float* node_b1 = (const float*)d_in[6];
  const float* node_w2 = (const float*)d_in[7];
  const float* node_b2 = (const float*)d_in[8];
  const float* edge_w1 = (const float*)d_in[9];
  const float* edge_b1 = (const float*)d_in[10];
  const float* edge_w2 = (const float*)d_in[11];
  const float* edge_b2 = (const float*)d_in[12];
  const float* eps     = (const float*)d_in[13];
  const float* gin_w1  = (const float*)d_in[14];
  const float* gin_b1  = (const float*)d_in[15];
  const float* gin_w2  = (const float*)d_in[16];
  const float* gin_b2  = (const float*)d_in[17];
  const float* elin_w  = (const float*)d_in[18];
  const float* elin_b  = (const float*)d_in[19];
  const float* aqkv_w  = (const float*)d_in[20];
  const float* aqkv_b  = (const float*)d_in[21];
  const float* aout_w  = (const float*)d_in[22];
  const float* aout_b  = (const float*)d_in[23];
  const float* mlp_w1  = (const float*)d_in[24];
  const float* mlp_b1  = (const float*)d_in[25];
  const float* mlp_w2  = (const float*)d_in[26];
  const float* mlp_b2  = (const float*)d_in[27];
  const float* ln1_g   = (const float*)d_in[28];
  const float* ln1_b   = (const float*)d_in[29];
  const float* ln2_g   = (const float*)d_in[30];
  const float* ln2_b   = (const float*)d_in[31];
  const float* ln3_g   = (const float*)d_in[32];
  const float* ln3_b   = (const float*)d_in[33];
  const float* post_w1 = (const float*)d_in[34];
  const float* post_b1 = (const float*)d_in[35];
  const float* post_w2 = (const float*)d_in[36];
  const float* post_b2 = (const float*)d_in[37];
  const float* ro_w1   = (const float*)d_in[38];
  const float* ro_b1   = (const float*)d_in[39];
  const float* ro_w2   = (const float*)d_in[40];
  const float* ro_b2   = (const float*)d_in[41];

  const int* src = edge_idx;
  const int* dst = edge_idx + E_;

  // Workspace (~102 MB): x | qkvb | hl | agg (fp32, dedicated) | attno_b (bf16, dedicated)
  //                      | fb2 | fw2tb | wt | ew1tb | ea_b | sort ints
  float* ws = (float*)d_ws;
  float* x     = ws;                                  // N*C
  unsigned short* qkvb = (unsigned short*)(x + (size_t)N_ * C_);  // N*384 bf16
  float* hl    = x + (size_t)N_ * C_ + (size_t)N_ * 192;          // N*C
  float* agg   = hl + (size_t)N_ * C_;                // N*C fp32 (dedicated)
  unsigned short* attno_b = (unsigned short*)(agg + (size_t)N_ * C_);  // N*C bf16
  float* fb2   = (float*)(attno_b + (size_t)N_ * C_); // 512 floats
  unsigned short* fw2tb = (unsigned short*)(fb2 + 4 * C_);  // 65536 bf16
  unsigned short* wt = fw2tb + (size_t)4 * C_ * C_;   // 655360 bf16
  unsigned short* ew1tb = wt + 655360;                // 4096 bf16
  unsigned short* ea_b = ew1tb + 4096;                // E*16 bf16
  int* src_s   = (int*)(ea_b + (size_t)E_ * ED_);     // E
  int* dst_s   = src_s + E_;                          // E
  int* hist    = dst_s + E_;                          // 32768
  int* binStart = hist + 32768;                       // 32769
  int* perm    = binStart + 32769;                    // E
  float* gsum  = hl;                                  // alias

  float* out = (float*)d_out;

  dim3 blk(128);
  const size_t LWS = 163840;

  k_fuse_w<<<4 * (C_ + 1), blk, 0, stream>>>(edge_w2, edge_b2, elin_w, elin_b, fw2tb, fb2);
  k_prep<<<4 * 1152, blk, 0, stream>>>(gin_w1, gin_w2, aqkv_w, aout_w, mlp_w1, mlp_w2, wt);
  k_prep_ew1<<<128, 32, 0, stream>>>(edge_w1, ew1tb);
  k_zero<<<(32768 / 4 + 255) / 256, 256, 0, stream>>>((float4*)hist, 32768 / 4);
  k_count<<<E_ / 256, 256, 0, stream>>>(dst, hist);
  k_scan<<<1, 1024, 0, stream>>>(hist, binStart);
  k_scatter<<<E_ / 256, 256, 0, stream>>>(dst, hist, perm);
  k_gather_edges<<<E_ / 256, 256, 0, stream>>>(edge_attr, src, dst, perm,
                                               ea_b, src_s, dst_s);
  k_zero<<<(N_ * C_ / 4 + 255) / 256, 256, 0, stream>>>((float4*)agg, N_ * C_ / 4);
  k_node_enc<<<N_ / 4, blk, 0, stream>>>(in_x, lap_pe, node_w1, node_b1, node_w2, node_b2, x);

  for (int i = 0; i < 4; ++i) {
    const unsigned short* wl = wt + (size_t)i * LWS;
    k_edge_mfma<<<E_ / 64, 256, 0, stream>>>(ea_b, x, src_s, dst_s,
                                             ew1tb, edge_b1,
                                             fw2tb + (size_t)i * C_ * C_, fb2 + i * C_, agg);
    k_ginqkv<<<N_ / 64, 256, 0, stream>>>(x, agg,
                                          wl + 0, gin_b1 + i * C_,
                                          wl + 16384, gin_b2 + i * C_,
                                          ln1_g + i * C_, ln1_b + i * C_, eps, i, hl,
                                          wl + 32768, aqkv_b + i * 384, qkvb);
    k_attn_mfma<<<B_ * 4 * 16, 256, 0, stream>>>(qkvb, attno_b);
    k_aoffn<<<N_ / 64, 256, 0, stream>>>(attno_b, x, hl,
                                         wl + 81920, aout_b + i * C_,
                                         ln2_g + i * C_, ln2_b + i * C_,
                                         wl + 98304, mlp_b1 + i * 256,
                                         wl + 131072, mlp_b2 + i * C_,
                                         ln3_g + i * C_, ln3_b + i * C_, agg);
  }

  k_zero<<<(B_ * C_ / 4 + 255) / 256, 256, 0, stream>>>((float4*)gsum, B_ * C_ / 4);
  k_post_pool<<<N_ / 4, blk, 0, stream>>>(x, post_w1, post_b1, post_w2, post_b2, gsum);
  k_readout<<<B_, blk, 0, stream>>>(gsum, ro_w1, ro_b1, ro_w2, ro_b2, out);
}